// Round 3
// baseline (46.841 us; speedup 1.0000x reference)
//
#include <hip/hip_runtime.h>
#include <math.h>

// Problem constants (fixed by the reference)
constexpr int B_ROWS = 16384;
constexpr int D_COLS = 2048;   // 512 float4 per row
constexpr float EPS_F = 1e-8f;
constexpr int P = 512;         // pass1 blocks; rows per block = 32
constexpr int RPB = B_ROWS / P;  // 32 contiguous rows per block

// ws float layout (every location plain-stored before read; no memset):
//  [0 .. 2048)            per-block counts, float4 per block {c0,c1,c2,c3}
//  [2048 .. 2048+1536)    per-pass2-block dot partials, 12 floats x 128 blocks
//  [16384 .. +P*8192)     per-pass1-block partials (float4-aligned)
constexpr int WS_DOTS = 2048;
constexpr int WS_PART = 16384;  // byte offset 65536, 16B aligned

// ---------------------------------------------------------------------------
// pass1: block b owns contiguous rows [32b, 32b+32). One-hot weights staged
// in LDS once; hot loop is branchless (1 float4 load + 16 FMA per row per
// thread) so the compiler can pipeline loads deeply.
// ---------------------------------------------------------------------------
__global__ __launch_bounds__(512) void pass1_partial_sums(
    const float* __restrict__ feat, const int* __restrict__ lab,
    const int* __restrict__ ses, float* __restrict__ ws) {
  const int t = threadIdx.x;
  const int b = blockIdx.x;
  const int row0 = b * RPB;

  __shared__ float4 w[RPB];
  if (t < RPB) {
    const int r = row0 + t;
    const int g = lab[r] * 2 + ses[r];
    w[t] = make_float4(g == 0 ? 1.f : 0.f, g == 1 ? 1.f : 0.f,
                       g == 2 ? 1.f : 0.f, g == 3 ? 1.f : 0.f);
  }
  __syncthreads();

  float4 a0 = {0.f, 0.f, 0.f, 0.f};
  float4 a1 = a0, a2 = a0, a3 = a0;

  const float4* fb = (const float4*)feat + (size_t)row0 * 512 + t;
  #pragma unroll 8
  for (int r = 0; r < RPB; ++r) {
    const float4 v = fb[(size_t)r * 512];
    const float4 wr = w[r];
    a0.x += v.x * wr.x; a0.y += v.y * wr.x; a0.z += v.z * wr.x; a0.w += v.w * wr.x;
    a1.x += v.x * wr.y; a1.y += v.y * wr.y; a1.z += v.z * wr.y; a1.w += v.w * wr.y;
    a2.x += v.x * wr.z; a2.y += v.y * wr.z; a2.z += v.z * wr.z; a2.w += v.w * wr.z;
    a3.x += v.x * wr.w; a3.y += v.y * wr.w; a3.z += v.z * wr.w; a3.w += v.w * wr.w;
  }

  float4* part = (float4*)(ws + WS_PART) + (size_t)b * 2048;
  part[t]        = a0;   // group g occupies float4 indices [g*512, g*512+512)
  part[512 + t]  = a1;
  part[1024 + t] = a2;
  part[1536 + t] = a3;

  if (t == 0) {
    float4 c = {0.f, 0.f, 0.f, 0.f};
    #pragma unroll
    for (int r = 0; r < RPB; ++r) {
      const float4 wr = w[r];
      c.x += wr.x; c.y += wr.y; c.z += wr.z; c.w += wr.w;
    }
    ((float4*)ws)[b] = c;   // plain store, no atomic
  }
}

// ---------------------------------------------------------------------------
// pass2: 128 blocks x 256 threads. Block owns 4 float4 columns (16 cols) of
// ALL 4 groups: thread t -> chunk=t>>4 (0..15), g=(t>>2)&3, cloc=t&3.
// Sums P partials, LDS-reduces chunks, then computes this block's partial
// contributions to the 10 dot products -> 12 floats out (no csum at all).
// ---------------------------------------------------------------------------
__global__ __launch_bounds__(256) void pass2_reduce(float* __restrict__ ws) {
  const int t = threadIdx.x;
  const int chunk = t >> 4;           // 0..15
  const int g = (t >> 2) & 3;         // group
  const int cloc = t & 3;             // column-of-block
  const int c = blockIdx.x * 4 + cloc;   // 0..511 float4 column
  const int j4 = g * 512 + c;

  float4 s = {0.f, 0.f, 0.f, 0.f};
  const float4* part = (const float4*)(ws + WS_PART);
  for (int p = chunk; p < P; p += 16) {
    const float4 v = part[(size_t)p * 2048 + j4];
    s.x += v.x; s.y += v.y; s.z += v.z; s.w += v.w;
  }

  __shared__ float4 lds[256];
  lds[t] = s;
  __syncthreads();

  __shared__ float4 sg[4][4];   // [g][cloc] = S_g for float4 column c
  if (t < 16) {
    float4 acc = lds[t];
    #pragma unroll
    for (int ch = 1; ch < 16; ++ch) {
      const float4 v = lds[ch * 16 + t];
      acc.x += v.x; acc.y += v.y; acc.z += v.z; acc.w += v.w;
    }
    sg[t >> 2][t & 3] = acc;
  }
  __syncthreads();

  if (t == 0) {
    float n0 = 0, n1 = 0, n2 = 0, n3 = 0;
    float d01 = 0, d23 = 0, d02 = 0, d03 = 0, d12 = 0, d13 = 0;
    #pragma unroll
    for (int cl = 0; cl < 4; ++cl) {
      const float4 s0 = sg[0][cl], s1 = sg[1][cl], s2 = sg[2][cl], s3 = sg[3][cl];
      n0 += s0.x*s0.x + s0.y*s0.y + s0.z*s0.z + s0.w*s0.w;
      n1 += s1.x*s1.x + s1.y*s1.y + s1.z*s1.z + s1.w*s1.w;
      n2 += s2.x*s2.x + s2.y*s2.y + s2.z*s2.z + s2.w*s2.w;
      n3 += s3.x*s3.x + s3.y*s3.y + s3.z*s3.z + s3.w*s3.w;
      d01 += s0.x*s1.x + s0.y*s1.y + s0.z*s1.z + s0.w*s1.w;
      d23 += s2.x*s3.x + s2.y*s3.y + s2.z*s3.z + s2.w*s3.w;
      d02 += s0.x*s2.x + s0.y*s2.y + s0.z*s2.z + s0.w*s2.w;
      d03 += s0.x*s3.x + s0.y*s3.y + s0.z*s3.z + s0.w*s3.w;
      d12 += s1.x*s2.x + s1.y*s2.y + s1.z*s2.z + s1.w*s2.w;
      d13 += s1.x*s3.x + s1.y*s3.y + s1.z*s3.z + s1.w*s3.w;
    }
    float* dst = ws + WS_DOTS + blockIdx.x * 12;
    dst[0] = n0;  dst[1] = n1;  dst[2] = n2;  dst[3] = n3;
    dst[4] = d01; dst[5] = d23; dst[6] = d02; dst[7] = d03;
    dst[8] = d12; dst[9] = d13; dst[10] = 0.f; dst[11] = 0.f;
  }
}

// ---------------------------------------------------------------------------
// pass3: sum 128 dot-partial records + P count records -> final scalars.
//   center_loss = 1 - (sum_g ||S_g||)/B          (uses ||f_i|| = 1)
// ---------------------------------------------------------------------------
__global__ __launch_bounds__(256) void pass3_finalize(
    const float* __restrict__ ws, float* __restrict__ out) {
  const int t = threadIdx.x;
  float n0 = 0, n1 = 0, n2 = 0, n3 = 0;
  float d01 = 0, d23 = 0, d02 = 0, d03 = 0, d12 = 0, d13 = 0;
  float k0 = 0, k1 = 0, k2 = 0, k3 = 0;

  if (t < 128) {
    const float* src = ws + WS_DOTS + t * 12;
    n0 = src[0]; n1 = src[1]; n2 = src[2]; n3 = src[3];
    d01 = src[4]; d23 = src[5]; d02 = src[6]; d03 = src[7];
    d12 = src[8]; d13 = src[9];
  }
  for (int p = t; p < P; p += 256) {
    const float4 c = ((const float4*)ws)[p];
    k0 += c.x; k1 += c.y; k2 += c.z; k3 += c.w;
  }

  #pragma unroll
  for (int m = 32; m >= 1; m >>= 1) {
    n0  += __shfl_xor(n0, m, 64);  n1  += __shfl_xor(n1, m, 64);
    n2  += __shfl_xor(n2, m, 64);  n3  += __shfl_xor(n3, m, 64);
    d01 += __shfl_xor(d01, m, 64); d23 += __shfl_xor(d23, m, 64);
    d02 += __shfl_xor(d02, m, 64); d03 += __shfl_xor(d03, m, 64);
    d12 += __shfl_xor(d12, m, 64); d13 += __shfl_xor(d13, m, 64);
    k0  += __shfl_xor(k0, m, 64);  k1  += __shfl_xor(k1, m, 64);
    k2  += __shfl_xor(k2, m, 64);  k3  += __shfl_xor(k3, m, 64);
  }

  __shared__ float red[4][14];
  const int wv = t >> 6, ln = t & 63;
  if (ln == 0) {
    red[wv][0] = n0;  red[wv][1] = n1;  red[wv][2] = n2;  red[wv][3] = n3;
    red[wv][4] = d01; red[wv][5] = d23; red[wv][6] = d02; red[wv][7] = d03;
    red[wv][8] = d12; red[wv][9] = d13;
    red[wv][10] = k0; red[wv][11] = k1; red[wv][12] = k2; red[wv][13] = k3;
  }
  __syncthreads();

  if (t == 0) {
    float v[14];
    #pragma unroll
    for (int k = 0; k < 14; ++k)
      v[k] = red[0][k] + red[1][k] + red[2][k] + red[3][k];

    const float NS0 = sqrtf(v[0]), NS1 = sqrtf(v[1]);
    const float NS2 = sqrtf(v[2]), NS3 = sqrtf(v[3]);
    const float cn0 = v[10], cn1 = v[11], cn2 = v[12], cn3 = v[13];
    const float N0 = NS0 / cn0, N1 = NS1 / cn1;
    const float N2 = NS2 / cn2, N3 = NS3 / cn3;

    const float c01 = (v[4] / (cn0 * cn1)) / fmaxf(N0 * N1, EPS_F);
    const float c23 = (v[5] / (cn2 * cn3)) / fmaxf(N2 * N3, EPS_F);
    const float c02 = (v[6] / (cn0 * cn2)) / fmaxf(N0 * N2, EPS_F);
    const float c03 = (v[7] / (cn0 * cn3)) / fmaxf(N0 * N3, EPS_F);
    const float c12 = (v[8] / (cn1 * cn2)) / fmaxf(N1 * N2, EPS_F);
    const float c13 = (v[9] / (cn1 * cn3)) / fmaxf(N1 * N3, EPS_F);

    const float center_loss = 1.0f - (NS0 + NS1 + NS2 + NS3) * (1.0f / (float)B_ROWS);
    const float align_loss = ((1.0f - c01) + (1.0f - c23)) * 0.5f;
    const float margin_loss = (c02 + c03 + c12 + c13) * 0.25f;

    out[0] = center_loss + 0.1f * align_loss + 0.05f * margin_loss;
    out[1] = center_loss;
    out[2] = align_loss;
    out[3] = margin_loss;
  }
}

extern "C" void kernel_launch(void* const* d_in, const int* in_sizes, int n_in,
                              void* d_out, int out_size, void* d_ws, size_t ws_size,
                              hipStream_t stream) {
  const float* feat = (const float*)d_in[0];
  const int* lab = (const int*)d_in[1];
  const int* ses = (const int*)d_in[2];
  float* ws = (float*)d_ws;
  float* out = (float*)d_out;

  // ws use: (16384 + 512*8192) * 4 B ~= 16.8 MB (harness provides far more).
  hipLaunchKernelGGL(pass1_partial_sums, dim3(P), dim3(512), 0, stream,
                     feat, lab, ses, ws);
  hipLaunchKernelGGL(pass2_reduce, dim3(128), dim3(256), 0, stream, ws);
  hipLaunchKernelGGL(pass3_finalize, dim3(1), dim3(256), 0, stream, ws, out);
}